// Round 1
// baseline (8089.086 us; speedup 1.0000x reference)
//
#include <hip/hip_runtime.h>

// RNN: s_{t+1} = 0.9*s + 0.1*(relu(s@Wrec^T + (u+inz)@Winp^T) + rn)
// states (B,T,N) fp32 then outputs (B,T,1) fp32, concatenated in d_out.
// Structure: batch-independent chains. 64 WGs x 512 threads, 2 batches/WG.
// Wrec pre-transposed into d_ws (Wt[k][n]) for coalesced float4 loads.
// Thread (n4,kc): owns n = 4*n4..4*n4+3, k-chunk kc*128..+128. LDS reduction
// over the 4 k-chunks. W_out dot fused per step (wave shuffle + LDS reduce).

#define NN 512
#define BB 128
#define TT 1000
#define NIN 6

__global__ void transpose_w(const float* __restrict__ W, float* __restrict__ Wt) {
  __shared__ float tile[32][33];
  const int bx = blockIdx.x * 32, by = blockIdx.y * 32;
  const int tx = threadIdx.x, ty = threadIdx.y;  // 32 x 8
  #pragma unroll
  for (int i = ty; i < 32; i += 8)
    tile[i][tx] = W[(size_t)(by + i) * NN + bx + tx];
  __syncthreads();
  #pragma unroll
  for (int i = ty; i < 32; i += 8)
    Wt[(size_t)(bx + i) * NN + by + tx] = tile[tx][i];
}

__device__ __forceinline__ float wave_sum(float v) {
  #pragma unroll
  for (int off = 32; off > 0; off >>= 1) v += __shfl_xor(v, off, 64);
  return v;
}

template <bool TRANS>
__global__ __launch_bounds__(512)
void rnn_fused(const float* __restrict__ u, const float* __restrict__ rnz,
               const float* __restrict__ inz, const float* __restrict__ Wsrc,
               const float* __restrict__ Winp, const float* __restrict__ Wout,
               const float* __restrict__ yinit,
               float* __restrict__ states, float* __restrict__ outputs) {
  const int tid = threadIdx.x;
  const int n4 = tid & 127;   // n-group (4 n's per thread)
  const int kc = tid >> 7;    // k-chunk 0..3 (uniform per wave)
  const int b0 = blockIdx.x * 2;
  const int b1 = b0 + 1;

  __shared__ __align__(16) float s[2][NN];
  __shared__ __align__(16) float red[2][128][20];  // 4 float4 chunks + pad
  __shared__ float ubuf[2 * NIN];
  __shared__ float outred[2][8];

  // per-thread constants: W_inp row, W_out element, y_init element (n = tid)
  float wi[NIN];
  #pragma unroll
  for (int j = 0; j < NIN; ++j) wi[j] = Winp[tid * NIN + j];
  const float wo = Wout[tid];
  const float yv = yinit[tid];

  // t = 0: states = y_init broadcast; outputs[b][0] = dot(y_init, wout)
  s[0][tid] = yv;
  s[1][tid] = yv;
  states[(size_t)(b0 * TT) * NN + tid] = yv;
  states[(size_t)(b1 * TT) * NN + tid] = yv;
  {
    float p = wave_sum(yv * wo);
    if ((tid & 63) == 0) outred[0][tid >> 6] = p;
  }
  __syncthreads();
  if (tid < 2) {
    float a = 0.f;
    #pragma unroll
    for (int w = 0; w < 8; ++w) a += outred[0][w];
    outputs[(tid ? b1 : b0) * TT] = a;
  }
  __syncthreads();

  for (int t = 0; t < TT - 1; ++t) {
    // ---- phase A: issue per-step global loads early (hidden by k-loop) ----
    const float rn0 = rnz[(size_t)(b0 * TT + t) * NN + tid];
    const float rn1 = rnz[(size_t)(b1 * TT + t) * NN + tid];
    float uv = 0.f;
    if (tid < 2 * NIN) {
      const int b = (tid < NIN) ? b0 : b1;
      const int j = (tid < NIN) ? tid : tid - NIN;
      const int idx = (b * TT + t) * NIN + j;
      uv = u[idx] + inz[idx];
    }

    // ---- phase A: partial matvec over this thread's k-chunk ----
    float a0[4] = {0.f, 0.f, 0.f, 0.f};
    float a1[4] = {0.f, 0.f, 0.f, 0.f};
    const int kbase0 = kc * 128;
    #pragma unroll 4
    for (int j4 = 0; j4 < 32; ++j4) {
      const int kb = kbase0 + j4 * 4;
      const float4 s0v = *reinterpret_cast<const float4*>(&s[0][kb]);
      const float4 s1v = *reinterpret_cast<const float4*>(&s[1][kb]);
      const float s0a[4] = {s0v.x, s0v.y, s0v.z, s0v.w};
      const float s1a[4] = {s1v.x, s1v.y, s1v.z, s1v.w};
      #pragma unroll
      for (int jj = 0; jj < 4; ++jj) {
        const int k = kb + jj;
        float4 w;
        if (TRANS) {
          w = *reinterpret_cast<const float4*>(Wsrc + (size_t)k * NN + (n4 << 2));
        } else {
          const float* p = Wsrc + (size_t)(n4 << 2) * NN + k;
          w.x = p[0]; w.y = p[NN]; w.z = p[2 * NN]; w.w = p[3 * NN];
        }
        a0[0] = fmaf(w.x, s0a[jj], a0[0]);
        a0[1] = fmaf(w.y, s0a[jj], a0[1]);
        a0[2] = fmaf(w.z, s0a[jj], a0[2]);
        a0[3] = fmaf(w.w, s0a[jj], a0[3]);
        a1[0] = fmaf(w.x, s1a[jj], a1[0]);
        a1[1] = fmaf(w.y, s1a[jj], a1[1]);
        a1[2] = fmaf(w.z, s1a[jj], a1[2]);
        a1[3] = fmaf(w.w, s1a[jj], a1[3]);
      }
    }
    if (tid < 2 * NIN) ubuf[tid] = uv;
    *reinterpret_cast<float4*>(&red[0][n4][kc << 2]) =
        make_float4(a0[0], a0[1], a0[2], a0[3]);
    *reinterpret_cast<float4*>(&red[1][n4][kc << 2]) =
        make_float4(a1[0], a1[1], a1[2], a1[3]);
    __syncthreads();  // #1: red + ubuf visible

    // ---- phase B: finalize n = tid ----
    const int n = tid;
    const int r = n >> 2, c = n & 3;
    float pre0 = (red[0][r][c] + red[0][r][4 + c]) +
                 (red[0][r][8 + c] + red[0][r][12 + c]);
    float pre1 = (red[1][r][c] + red[1][r][4 + c]) +
                 (red[1][r][8 + c] + red[1][r][12 + c]);
    #pragma unroll
    for (int j = 0; j < NIN; ++j) {
      pre0 = fmaf(ubuf[j], wi[j], pre0);
      pre1 = fmaf(ubuf[NIN + j], wi[j], pre1);
    }
    const float sn0 = 0.9f * s[0][n] + 0.1f * (fmaxf(pre0, 0.f) + rn0);
    const float sn1 = 0.9f * s[1][n] + 0.1f * (fmaxf(pre1, 0.f) + rn1);
    states[(size_t)(b0 * TT + t + 1) * NN + n] = sn0;
    states[(size_t)(b1 * TT + t + 1) * NN + n] = sn1;
    s[0][n] = sn0;  // only thread n reads/writes s[.][n] in phase B: safe
    s[1][n] = sn1;
    float p0 = wave_sum(sn0 * wo);
    float p1 = wave_sum(sn1 * wo);
    if ((tid & 63) == 0) {
      outred[0][tid >> 6] = p0;
      outred[1][tid >> 6] = p1;
    }
    __syncthreads();  // #2: s + outred visible
    if (tid < 2) {
      float a = 0.f;
      #pragma unroll
      for (int w = 0; w < 8; ++w) a += outred[tid][w];
      outputs[(tid ? b1 : b0) * TT + t + 1] = a;
    }
  }
}

extern "C" void kernel_launch(void* const* d_in, const int* in_sizes, int n_in,
                              void* d_out, int out_size, void* d_ws, size_t ws_size,
                              hipStream_t stream) {
  const float* u    = (const float*)d_in[0];
  const float* rnz  = (const float*)d_in[1];
  const float* inz  = (const float*)d_in[2];
  const float* Wrec = (const float*)d_in[3];
  const float* Winp = (const float*)d_in[4];
  const float* Wout = (const float*)d_in[5];
  const float* yin  = (const float*)d_in[6];
  float* states  = (float*)d_out;
  float* outputs = states + (size_t)BB * TT * NN;

  const bool use_t = ws_size >= (size_t)NN * NN * sizeof(float);
  if (use_t) {
    float* Wt = (float*)d_ws;
    transpose_w<<<dim3(16, 16), dim3(32, 8), 0, stream>>>(Wrec, Wt);
    rnn_fused<true><<<BB / 2, 512, 0, stream>>>(u, rnz, inz, Wt, Winp, Wout,
                                                yin, states, outputs);
  } else {
    rnn_fused<false><<<BB / 2, 512, 0, stream>>>(u, rnz, inz, Wrec, Winp, Wout,
                                                 yin, states, outputs);
  }
}